// Round 1
// baseline (1169.859 us; speedup 1.0000x reference)
//
#include <hip/hip_runtime.h>
#include <hip/hip_bf16.h>

#define B_    1024
#define H_    1024
#define VOUT  50000
#define VINP  32000
#define SRC_  256

#define BM 128
#define BN 128
#define BKK 32
#define LDK 40   // padded LDS leading dim in bf16 elems (128 rows x 40)

typedef __bf16 bf16x8 __attribute__((ext_vector_type(8)));
typedef __bf16 bf16x4 __attribute__((ext_vector_type(4)));
typedef float  f32x4  __attribute__((ext_vector_type(4)));

// ---------------- src_inp build (last-occurrence-wins for ptr_scores set) ---
__global__ void init_src_kernel(int* __restrict__ src_inp) {
    int i = blockIdx.x * blockDim.x + threadIdx.x;
    if (i < VOUT) src_inp[i] = -1;
}

__global__ void scat_max_kernel(const int* __restrict__ i2a, int* __restrict__ src_inp) {
    int v = blockIdx.x * blockDim.x + threadIdx.x;
    if (v < VINP) atomicMax(&src_inp[i2a[v]], v);
}

// ---------------- GEMM: out_scores = x @ W[out_map].T + b[out_map] ----------
// also writes gen_masked = out_scores - 1e6*actionmask  (pre-ptr scores)
__global__ __launch_bounds__(256) void gemm_kernel(
    const float* __restrict__ x, const float* __restrict__ W,
    const float* __restrict__ bias, const int* __restrict__ out_map,
    const int* __restrict__ amask,
    float* __restrict__ out_scores, float* __restrict__ gen_masked)
{
    __shared__ __bf16 As[BM * LDK];
    __shared__ __bf16 Bs[BN * LDK];

    const int t  = threadIdx.x;
    const int m0 = blockIdx.x * BM;   // grid.x = 8 (fast dim -> shares W tile)
    const int n0 = blockIdx.y * BN;   // grid.y = 391

    const int tr = t >> 3;            // 0..31
    const int tk = (t & 7) << 2;      // 0,4,..,28

    const float* xrow[4];
    const float* wrow[4];
    #pragma unroll
    for (int p = 0; p < 4; ++p) {
        int r = tr + p * 32;
        xrow[p] = x + (size_t)(m0 + r) * H_ + tk;
        int n = n0 + r; if (n >= VOUT) n = VOUT - 1;
        int om = out_map[n];
        wrow[p] = W + (size_t)om * H_ + tk;
    }

    f32x4 acc[4][4];
    #pragma unroll
    for (int i = 0; i < 4; ++i)
        #pragma unroll
        for (int j = 0; j < 4; ++j)
            acc[i][j] = (f32x4){0.f, 0.f, 0.f, 0.f};

    const int wv   = t >> 6;
    const int wm   = (wv >> 1) * 64;
    const int wn   = (wv & 1) * 64;
    const int lane = t & 63;
    const int quad = lane >> 4;
    const int lr   = lane & 15;

    for (int k0 = 0; k0 < H_; k0 += BKK) {
        #pragma unroll
        for (int p = 0; p < 4; ++p) {
            int r = tr + p * 32;
            const float4 av = *(const float4*)(xrow[p] + k0);
            const float4 bv = *(const float4*)(wrow[p] + k0);
            bf16x4 a4, b4;
            a4.x = (__bf16)av.x; a4.y = (__bf16)av.y; a4.z = (__bf16)av.z; a4.w = (__bf16)av.w;
            b4.x = (__bf16)bv.x; b4.y = (__bf16)bv.y; b4.z = (__bf16)bv.z; b4.w = (__bf16)bv.w;
            *(bf16x4*)(&As[r * LDK + tk]) = a4;
            *(bf16x4*)(&Bs[r * LDK + tk]) = b4;
        }
        __syncthreads();

        bf16x8 af[4], bfr[4];
        #pragma unroll
        for (int i = 0; i < 4; ++i) {
            af[i]  = *(const bf16x8*)(&As[(wm + i * 16 + lr) * LDK + quad * 8]);
            bfr[i] = *(const bf16x8*)(&Bs[(wn + i * 16 + lr) * LDK + quad * 8]);
        }
        #pragma unroll
        for (int mi = 0; mi < 4; ++mi)
            #pragma unroll
            for (int ni = 0; ni < 4; ++ni)
                acc[mi][ni] = __builtin_amdgcn_mfma_f32_16x16x32_bf16(af[mi], bfr[ni], acc[mi][ni], 0, 0, 0);
        __syncthreads();
    }

    // epilogue: C/D layout col = lane&15, row = quad*4 + reg
    #pragma unroll
    for (int ni = 0; ni < 4; ++ni) {
        int n = n0 + wn + ni * 16 + lr;
        if (n >= VOUT) continue;
        float bb = bias[out_map[n]];
        #pragma unroll
        for (int mi = 0; mi < 4; ++mi) {
            int mbase = m0 + wm + mi * 16 + quad * 4;
            #pragma unroll
            for (int r = 0; r < 4; ++r) {
                size_t off = (size_t)(mbase + r) * VOUT + n;
                float v = acc[mi][ni][r] + bb;
                out_scores[off] = v;
                gen_masked[off] = v - 1000000.0f * (float)amask[off];
            }
        }
    }
}

// ---------------- ptr scatter-add into out_scores ---------------------------
__global__ void ptr_scatter_kernel(const float* __restrict__ attn,
                                   const int* __restrict__ ctx,
                                   const int* __restrict__ i2a,
                                   const int* __restrict__ src_inp,
                                   float* __restrict__ out_scores)
{
    int idx = blockIdx.x * blockDim.x + threadIdx.x;   // B*SRC threads
    int i = idx >> 8;
    int v = ctx[idx];
    int o = i2a[v];
    if (src_inp[o] == v)
        atomicAdd(out_scores + (size_t)i * VOUT + o, attn[idx]);
}

// ---------------- row softmax in place --------------------------------------
__global__ __launch_bounds__(256) void softmax_kernel(float* __restrict__ probs)
{
    const int row = blockIdx.x;
    float* p = probs + (size_t)row * VOUT;
    float4* p4 = (float4*)p;
    const int N4 = VOUT / 4;   // 12500 exactly
    const int t = threadIdx.x;
    __shared__ float red[256];

    // pass 1: max
    float m = -1e30f;
    for (int i = t; i < N4; i += 256) {
        float4 v = p4[i];
        m = fmaxf(m, fmaxf(fmaxf(v.x, v.y), fmaxf(v.z, v.w)));
    }
    red[t] = m; __syncthreads();
    for (int s = 128; s > 0; s >>= 1) {
        if (t < s) red[t] = fmaxf(red[t], red[t + s]);
        __syncthreads();
    }
    m = red[0]; __syncthreads();

    // pass 2: sum of exp
    float sum = 0.f;
    for (int i = t; i < N4; i += 256) {
        float4 v = p4[i];
        sum += __expf(v.x - m) + __expf(v.y - m) + __expf(v.z - m) + __expf(v.w - m);
    }
    red[t] = sum; __syncthreads();
    for (int s = 128; s > 0; s >>= 1) {
        if (t < s) red[t] += red[t + s];
        __syncthreads();
    }
    float inv = 1.0f / red[0];
    __syncthreads();

    // pass 3: normalize
    for (int i = t; i < N4; i += 256) {
        float4 v = p4[i];
        v.x = __expf(v.x - m) * inv;
        v.y = __expf(v.y - m) * inv;
        v.z = __expf(v.z - m) * inv;
        v.w = __expf(v.w - m) * inv;
        p4[i] = v;
    }
}

// ---------------- launch ----------------------------------------------------
extern "C" void kernel_launch(void* const* d_in, const int* in_sizes, int n_in,
                              void* d_out, int out_size, void* d_ws, size_t ws_size,
                              hipStream_t stream)
{
    const float* x     = (const float*)d_in[0];
    const float* W     = (const float*)d_in[1];
    const float* b     = (const float*)d_in[2];
    const float* attn  = (const float*)d_in[3];
    const int*   ctx   = (const int*)d_in[4];
    const int*   i2a   = (const int*)d_in[5];
    const int*   omap  = (const int*)d_in[6];
    const int*   amask = (const int*)d_in[7];

    float* out_probs  = (float*)d_out;                       // B*VOUT
    float* gen_masked = out_probs + (size_t)B_ * VOUT;       // B*VOUT

    int* src_inp = (int*)d_ws;                               // VOUT ints

    init_src_kernel<<<(VOUT + 255) / 256, 256, 0, stream>>>(src_inp);
    scat_max_kernel<<<(VINP + 255) / 256, 256, 0, stream>>>(i2a, src_inp);

    dim3 grid(B_ / BM, (VOUT + BN - 1) / BN);                // (8, 391)
    gemm_kernel<<<grid, 256, 0, stream>>>(x, W, b, omap, amask, out_probs, gen_masked);

    ptr_scatter_kernel<<<(B_ * SRC_) / 256, 256, 0, stream>>>(attn, ctx, i2a, src_inp, out_probs);

    softmax_kernel<<<B_, 256, 0, stream>>>(out_probs);
}